// Round 12
// baseline (742.696 us; speedup 1.0000x reference)
//
#include <hip/hip_runtime.h>

// GraphEncoder: MHA + 3×(GAT + residual-proj + LN[+ELU]).
// B=64, N=400, D=400, Hd=256, E=128, H=4, hd=64.
// Full bf16 dataflow; GAT tail fused; all GEMM A-operands bf16.
// d_out layout (f32): x_final [64*400*128] | attn1 [64*400*400] | attn2 | attn3

#define NEGBIG (-1e9f)

typedef __attribute__((ext_vector_type(8))) short bf16x8;
typedef __attribute__((ext_vector_type(4))) float f32x4;

__device__ inline unsigned short f2bf(float f) {
    unsigned u = __builtin_bit_cast(unsigned, f);
    u += 0x7fffu + ((u >> 16) & 1u);          // RNE
    return (unsigned short)(u >> 16);
}
__device__ inline float bf2f(unsigned short h) {
    unsigned u = ((unsigned)h) << 16;
    return __builtin_bit_cast(float, u);
}

__device__ inline float wave_sum(float v) {
#pragma unroll
    for (int off = 32; off >= 1; off >>= 1)
        v += __shfl_xor(v, off, 64);
    return v;
}
__device__ inline float wave_max(float v) {
#pragma unroll
    for (int off = 32; off >= 1; off >>= 1)
        v = fmaxf(v, __shfl_xor(v, off, 64));
    return v;
}

// ---------------------------------------------------------------------------
__global__ void build_biases(
    float* bqkv, const float* bq, const float* bk, const float* bv,
    float* bgr1, const float* r1b, float* bgr2, const float* r2b,
    float* bgr3, const float* r3b)
{
    const int t = threadIdx.x;
    bqkv[t] = bq[t]; bqkv[256 + t] = bk[t]; bqkv[512 + t] = bv[t];
    bgr1[t] = 0.f; bgr1[256 + t] = r1b[t];
    bgr2[t] = 0.f; bgr2[256 + t] = r2b[t];
    if (t < 128) { bgr3[t] = 0.f; bgr3[128 + t] = r3b[t]; }
}

// f32 -> bf16 rowwise copy (count divisible by 1024)
__global__ __launch_bounds__(256) void f32_to_bf16(
    const float* __restrict__ in, unsigned short* __restrict__ out)
{
    const long i = ((long)blockIdx.x * 256 + threadIdx.x) * 4;
    const float4 a = *reinterpret_cast<const float4*>(in + i);
    ushort4 o;
    o.x = f2bf(a.x); o.y = f2bf(a.y); o.z = f2bf(a.z); o.w = f2bf(a.w);
    *reinterpret_cast<ushort4*>(out + i) = o;
}

// adj f32 -> additive maskbias bf16 (0 where edge, -1e9 where none)
__global__ __launch_bounds__(256) void adj2mask(
    const float* __restrict__ adj, unsigned short* __restrict__ mb)
{
    const long i = ((long)blockIdx.x * 256 + threadIdx.x) * 4;
    const float4 a = *reinterpret_cast<const float4*>(adj + i);
    ushort4 o;
    o.x = f2bf(a.x > 0.f ? 0.f : NEGBIG);
    o.y = f2bf(a.y > 0.f ? 0.f : NEGBIG);
    o.z = f2bf(a.z > 0.f ? 0.f : NEGBIG);
    o.w = f2bf(a.w > 0.f ? 0.f : NEGBIG);
    *reinterpret_cast<ushort4*>(mb + i) = o;
}

// ---------------------------------------------------------------------------
// Transpose + f32->bf16: out[c][r] = bf16(in[r][c]). (weights only)
__global__ __launch_bounds__(256) void transpose_to_bf16(
    const float* __restrict__ in, unsigned short* __restrict__ out,
    int R, int C, int ldIn)
{
    __shared__ float t[32][33];
    const int r0 = blockIdx.y * 32, c0 = blockIdx.x * 32;
    const int tid = threadIdx.x;

    const int row = tid >> 3, c4 = tid & 7;
    float4 v = make_float4(0.f, 0.f, 0.f, 0.f);
    if (r0 + row < R && c0 + c4 * 4 < C)
        v = *reinterpret_cast<const float4*>(&in[(long)(r0 + row) * ldIn + c0 + c4 * 4]);
    t[row][c4 * 4 + 0] = v.x;
    t[row][c4 * 4 + 1] = v.y;
    t[row][c4 * 4 + 2] = v.z;
    t[row][c4 * 4 + 3] = v.w;
    __syncthreads();

    const int oc = tid >> 3, r4 = tid & 7;
    if (c0 + oc < C && r0 + r4 * 4 < R) {
        ushort4 o;
        o.x = f2bf(t[r4 * 4 + 0][oc]);
        o.y = f2bf(t[r4 * 4 + 1][oc]);
        o.z = f2bf(t[r4 * 4 + 2][oc]);
        o.w = f2bf(t[r4 * 4 + 3][oc]);
        *reinterpret_cast<ushort4*>(&out[(long)(c0 + oc) * R + r0 + r4 * 4]) = o;
    }
}

// ---------------------------------------------------------------------------
// C[M,Nc] = A[M,K](bf16) @ BT[Nc,K](bf16)  (+bias)(+resid f32)
// Tile 64x256x32, 256 threads = 4 waves (1x4), wave 64x64, mfma 16x16x32.
// M must be a multiple of 64 (M=25600); Nc guarded; K%8==0.
template<bool BIAS, bool RESID, bool OUTBF16>
__global__ __launch_bounds__(256) void gemm_mfma(
    const unsigned short* __restrict__ A, const unsigned short* __restrict__ BT,
    const float* __restrict__ bias, const float* __restrict__ resid,
    void* __restrict__ Cv, int K, int Nc, int ldA, int ldC)
{
    float* Cf = OUTBF16 ? nullptr : (float*)Cv;
    unsigned short* Ch = OUTBF16 ? (unsigned short*)Cv : nullptr;

    __shared__ short As[64][40];
    __shared__ short Bs[256][40];

    const int tid = threadIdx.x;
    const int lane = tid & 63, wn = tid >> 6;
    const int m0 = blockIdx.y * 64, n0 = blockIdx.x * 256;

    f32x4 acc[4][4] = {};

    const int nk = (K + 31) / 32;
    for (int kt = 0; kt < nk; ++kt) {
        const int k0 = kt * 32;
        __syncthreads();
        // stage A: 64 rows x 4 x 16B
        {
            const int row = tid >> 2, k8 = tid & 3;
            const int gk = k0 + k8 * 8;
            uint4 av = make_uint4(0u, 0u, 0u, 0u);
            if (gk < K)
                av = *reinterpret_cast<const uint4*>(&A[(long)(m0 + row) * ldA + gk]);
            *reinterpret_cast<uint4*>(&As[row][k8 * 8]) = av;
        }
        // stage B: 256 rows x 4 x 16B
#pragma unroll
        for (int p = 0; p < 4; ++p) {
            const int idx = tid + p * 256;
            const int n = idx >> 2, k8 = idx & 3;
            const int gn = n0 + n, gk = k0 + k8 * 8;
            uint4 bv = make_uint4(0u, 0u, 0u, 0u);
            if (gn < Nc && gk < K)
                bv = *reinterpret_cast<const uint4*>(&BT[(long)gn * K + gk]);
            *reinterpret_cast<uint4*>(&Bs[n][k8 * 8]) = bv;
        }
        __syncthreads();

        const int fr = lane & 15, fkb = (lane >> 4) * 8;
        bf16x8 a[4], b[4];
#pragma unroll
        for (int i = 0; i < 4; ++i)
            a[i] = *reinterpret_cast<const bf16x8*>(&As[i * 16 + fr][fkb]);
#pragma unroll
        for (int j = 0; j < 4; ++j)
            b[j] = *reinterpret_cast<const bf16x8*>(&Bs[wn * 64 + j * 16 + fr][fkb]);
#pragma unroll
        for (int i = 0; i < 4; ++i)
#pragma unroll
            for (int j = 0; j < 4; ++j)
                acc[i][j] = __builtin_amdgcn_mfma_f32_16x16x32_bf16(a[i], b[j], acc[i][j], 0, 0, 0);
    }

    const int fr = lane & 15, rg = lane >> 4;
#pragma unroll
    for (int i = 0; i < 4; ++i) {
#pragma unroll
        for (int j = 0; j < 4; ++j) {
#pragma unroll
            for (int r = 0; r < 4; ++r) {
                const int gm = m0 + i * 16 + rg * 4 + r;
                const int gn = n0 + wn * 64 + j * 16 + fr;
                if (gn < Nc) {
                    float v = acc[i][j][r];
                    if (BIAS)  v += bias[gn];
                    if (RESID) v += resid[(long)gm * ldC + gn];
                    if (OUTBF16) Ch[(long)gm * ldC + gn] = f2bf(v);
                    else         Cf[(long)gm * ldC + gn] = v;
                }
            }
        }
    }
}

// ---------------------------------------------------------------------------
// Flash MHA on MFMA, bf16 in/out. qkv bf16 [25600][768]; mask bf16 additive.
__global__ __launch_bounds__(256) void mha_flash_mfma(
    const unsigned short* __restrict__ qkv, const unsigned short* __restrict__ mask,
    unsigned short* __restrict__ ctx, int ld)
{
    const int it = blockIdx.x, h = blockIdx.y, b = blockIdx.z;
    const int i0 = it * 64;
    const int tid = threadIdx.x;
    const int lane = tid & 63, w = tid >> 6;
    const int c = lane & 15, g = lane >> 4;
    const unsigned short NEGBF = f2bf(NEGBIG);

    __shared__ short Qs[64][72];
    __shared__ short Ks[64][72];
    __shared__ short Vt[64][72];
    __shared__ short Ps[64][72];
    __shared__ short Adjs[64][72];

    const long base_q = ((long)b * 400 + i0) * ld + h * 64;
#pragma unroll
    for (int p = 0; p < 2; ++p) {
        const int idx = tid + p * 256;
        const int r = idx >> 3, c8 = idx & 7;
        uint4 qv = make_uint4(0u, 0u, 0u, 0u);
        if (i0 + r < 400)
            qv = *reinterpret_cast<const uint4*>(qkv + base_q + (long)r * ld + c8 * 8);
        *reinterpret_cast<uint4*>(&Qs[r][c8 * 8]) = qv;
    }

    f32x4 o[4] = {};
    float m[4] = {-3e38f, -3e38f, -3e38f, -3e38f};
    float l[4] = {0.f, 0.f, 0.f, 0.f};

    for (int jt = 0; jt < 7; ++jt) {
        const int j0 = jt * 64;
        __syncthreads();

        const long base_k = ((long)b * 400 + j0) * ld + 256 + h * 64;
        const long base_v = base_k + 256;
#pragma unroll
        for (int p = 0; p < 2; ++p) {
            const int idx = tid + p * 256;
            const int r = idx >> 3, c8 = idx & 7;
            uint4 kv = make_uint4(0u, 0u, 0u, 0u);
            if (j0 + r < 400)
                kv = *reinterpret_cast<const uint4*>(qkv + base_k + (long)r * ld + c8 * 8);
            *reinterpret_cast<uint4*>(&Ks[r][c8 * 8]) = kv;

            ushort4 mb = make_ushort4(NEGBF, NEGBF, NEGBF, NEGBF);
            ushort4 mb2 = mb;
            if (i0 + r < 400 && j0 + c8 * 8 + 7 < 400) {
                const uint4 mv = *reinterpret_cast<const uint4*>(
                    mask + ((long)b * 400 + i0 + r) * 400 + j0 + c8 * 8);
                mb  = *reinterpret_cast<const ushort4*>(&mv.x);
                mb2 = *reinterpret_cast<const ushort4*>(&mv.z);
            }
            *reinterpret_cast<ushort4*>(&Adjs[r][c8 * 8]) = mb;
            *reinterpret_cast<ushort4*>(&Adjs[r][c8 * 8 + 4]) = mb2;
        }
        {
            const int j4 = tid >> 4, d4 = tid & 15;
            ushort4 vl[4];
#pragma unroll
            for (int t = 0; t < 4; ++t) {
                vl[t] = make_ushort4(0, 0, 0, 0);
                if (j0 + j4 * 4 + t < 400)
                    vl[t] = *reinterpret_cast<const ushort4*>(qkv + base_v + (long)(j4 * 4 + t) * ld + d4 * 4);
            }
#pragma unroll
            for (int u = 0; u < 4; ++u) {
                ushort4 h4;
                h4.x = ((const unsigned short*)&vl[0])[u];
                h4.y = ((const unsigned short*)&vl[1])[u];
                h4.z = ((const unsigned short*)&vl[2])[u];
                h4.w = ((const unsigned short*)&vl[3])[u];
                *reinterpret_cast<ushort4*>(&Vt[d4 * 4 + u][j4 * 4]) = h4;
            }
        }
        __syncthreads();

        f32x4 s4[4] = {};
#pragma unroll
        for (int ks = 0; ks < 2; ++ks) {
            const bf16x8 a = *reinterpret_cast<const bf16x8*>(&Qs[w * 16 + c][ks * 32 + g * 8]);
#pragma unroll
            for (int t = 0; t < 4; ++t) {
                const bf16x8 bb = *reinterpret_cast<const bf16x8*>(&Ks[t * 16 + c][ks * 32 + g * 8]);
                s4[t] = __builtin_amdgcn_mfma_f32_16x16x32_bf16(a, bb, s4[t], 0, 0, 0);
            }
        }

        float e[4][4];
        float pmax[4];
#pragma unroll
        for (int reg = 0; reg < 4; ++reg) {
            const int qr = w * 16 + g * 4 + reg;
            float mx = -3e38f;
#pragma unroll
            for (int t = 0; t < 4; ++t) {
                const float ev = s4[t][reg] * 0.125f + bf2f((unsigned short)Adjs[qr][t * 16 + c]);
                e[t][reg] = ev;
                mx = fmaxf(mx, ev);
            }
            pmax[reg] = mx;
        }
#pragma unroll
        for (int reg = 0; reg < 4; ++reg)
#pragma unroll
            for (int off = 1; off <= 8; off <<= 1)
                pmax[reg] = fmaxf(pmax[reg], __shfl_xor(pmax[reg], off, 64));

        float al[4];
#pragma unroll
        for (int reg = 0; reg < 4; ++reg) {
            const float mn = fmaxf(m[reg], pmax[reg]);
            al[reg] = __expf(m[reg] - mn);
            m[reg] = mn;
        }

#pragma unroll
        for (int reg = 0; reg < 4; ++reg) {
            const int qr = w * 16 + g * 4 + reg;
            float psum = 0.f;
#pragma unroll
            for (int t = 0; t < 4; ++t) {
                const float p = __expf(e[t][reg] - m[reg]);
                psum += p;
                Ps[qr][t * 16 + c] = (short)f2bf(p);
            }
            l[reg] = l[reg] * al[reg] + psum;
        }

#pragma unroll
        for (int dt = 0; dt < 4; ++dt)
#pragma unroll
            for (int reg = 0; reg < 4; ++reg)
                o[dt][reg] *= al[reg];

#pragma unroll
        for (int ks = 0; ks < 2; ++ks) {
            const bf16x8 a = *reinterpret_cast<const bf16x8*>(&Ps[w * 16 + c][ks * 32 + g * 8]);
#pragma unroll
            for (int dt = 0; dt < 4; ++dt) {
                const bf16x8 bb = *reinterpret_cast<const bf16x8*>(&Vt[dt * 16 + c][ks * 32 + g * 8]);
                o[dt] = __builtin_amdgcn_mfma_f32_16x16x32_bf16(a, bb, o[dt], 0, 0, 0);
            }
        }
    }

#pragma unroll
    for (int reg = 0; reg < 4; ++reg)
#pragma unroll
        for (int off = 1; off <= 8; off <<= 1)
            l[reg] += __shfl_xor(l[reg], off, 64);

#pragma unroll
    for (int reg = 0; reg < 4; ++reg) {
        const int gi = i0 + w * 16 + g * 4 + reg;
        if (gi < 400) {
            const float inv = 1.f / l[reg];
#pragma unroll
            for (int dt = 0; dt < 4; ++dt)
                ctx[((long)b * 400 + gi) * 256 + h * 64 + dt * 16 + c] = f2bf(o[dt][reg] * inv);
        }
    }
}

// src/dst projections from bf16 h (row stride 2F).
template<int F>
__global__ __launch_bounds__(256) void gat_srcdst_h(
    const unsigned short* __restrict__ h, const float* __restrict__ a,
    float* __restrict__ src, float* __restrict__ dst)
{
    const int row = blockIdx.x * 4 + (threadIdx.x >> 6);
    const int lane = threadIdx.x & 63;
    constexpr int PER = F / 64;
    const unsigned short* hp = h + (long)row * (2 * F) + lane * PER;
    float s = 0.f, d = 0.f;
#pragma unroll
    for (int u = 0; u < PER; ++u) {
        const float hv = bf2f(hp[u]);
        s += hv * a[lane * PER + u];
        d += hv * a[F + lane * PER + u];
    }
    s = wave_sum(s);
    d = wave_sum(d);
    if (lane == 0) { src[row] = s; dst[row] = d; }
}

// ---------------------------------------------------------------------------
// Fused GAT tail: row-softmax (attn out f32) + PV (MFMA) + residual + LN(+ELU).
// Grid (7 i-tiles, 64 batches), 256 threads = 4 waves; wave w owns rows w*16..+15.
// hr bf16 [B*400][2F]: h cols 0..F-1, res cols F..2F-1.
template<int F, bool ELU, bool OUTB16>
__global__ __launch_bounds__(256) void gat_fused(
    const float* __restrict__ src, const float* __restrict__ dst,
    const unsigned short* __restrict__ mask,
    const unsigned short* __restrict__ hr,
    const float* __restrict__ gam, const float* __restrict__ bet,
    float* __restrict__ attn, void* __restrict__ xout)
{
    constexpr int LD = 2 * F;
    constexpr int DT = F / 16;       // col tiles
    constexpr int DG = F / 4;        // d-groups per k-step staging
    constexpr int NP = (8 * DG) / 256;

    const int it = blockIdx.x, b = blockIdx.y;
    const int i0 = it * 64;
    const int tid = threadIdx.x;
    const int lane = tid & 63, w = tid >> 6;
    const int c = lane & 15, g = lane >> 4;

    __shared__ short Ps[64][424];    // P bf16, wave-private row bands
    __shared__ short Ht[F][40];      // h^T tile for current k-step

    // ---- softmax phase
    const float* drow = dst + (long)b * 400;
    for (int rr = 0; rr < 16; ++rr) {
        const int r = w * 16 + rr;
        const int gi = i0 + r;
        const int giq = gi < 400 ? gi : 399;
        const float si = src[(long)b * 400 + giq];
        const unsigned short* mrow = mask + ((long)b * 400 + giq) * 400;
        float e[7];
        float mx = -3e38f;
#pragma unroll
        for (int t = 0; t < 7; ++t) {
            const int j = lane + 64 * t;
            float v = -3e38f;
            if (j < 400) {
                v = si + drow[j];
                v = (v > 0.f) ? v : 0.2f * v;
                v += bf2f(mrow[j]);
            }
            e[t] = v;
            mx = fmaxf(mx, v);
        }
        mx = wave_max(mx);
        float p[7], sum = 0.f;
#pragma unroll
        for (int t = 0; t < 7; ++t) {
            const int j = lane + 64 * t;
            if (j < 400) { p[t] = __expf(e[t] - mx); sum += p[t]; }
        }
        sum = wave_sum(sum);
        const float inv = 1.f / sum;
#pragma unroll
        for (int t = 0; t < 7; ++t) {
            const int j = lane + 64 * t;
            if (j < 400) {
                const float pv = p[t] * inv;
                if (gi < 400) attn[((long)b * 400 + gi) * 400 + j] = pv;
                Ps[r][j] = (short)f2bf(pv);
            } else if (j < 416) {
                Ps[r][j] = 0;
            }
        }
    }

    // ---- PV phase: O = P @ h, K=400 in 13 steps of 32
    f32x4 acc[DT] = {};
    const long hbase = (long)b * 400 * LD;
    for (int kt = 0; kt < 13; ++kt) {
        const int k0 = kt * 32;
        __syncthreads();
#pragma unroll
        for (int p = 0; p < NP; ++p) {
            const int slot = tid + p * 256;
            const int kg = slot / DG, dg = slot % DG;
            ushort4 vl[4];
#pragma unroll
            for (int t = 0; t < 4; ++t) {
                const int j = k0 + kg * 4 + t;
                vl[t] = make_ushort4(0, 0, 0, 0);
                if (j < 400)
                    vl[t] = *reinterpret_cast<const ushort4*>(&hr[hbase + (long)j * LD + dg * 4]);
            }
#pragma unroll
            for (int u = 0; u < 4; ++u) {
                ushort4 h4;
                h4.x = ((const unsigned short*)&vl[0])[u];
                h4.y = ((const unsigned short*)&vl[1])[u];
                h4.z = ((const unsigned short*)&vl[2])[u];
                h4.w = ((const unsigned short*)&vl[3])[u];
                *reinterpret_cast<ushort4*>(&Ht[dg * 4 + u][kg * 4]) = h4;
            }
        }
        __syncthreads();

        const bf16x8 a = *reinterpret_cast<const bf16x8*>(&Ps[w * 16 + c][k0 + g * 8]);
#pragma unroll
        for (int dt = 0; dt < DT; ++dt) {
            const bf16x8 bb = *reinterpret_cast<const bf16x8*>(&Ht[dt * 16 + c][g * 8]);
            acc[dt] = __builtin_amdgcn_mfma_f32_16x16x32_bf16(a, bb, acc[dt], 0, 0, 0);
        }
    }

    // ---- epilogue: + res, LayerNorm(+ELU), store
#pragma unroll
    for (int reg = 0; reg < 4; ++reg) {
        const int row = w * 16 + g * 4 + reg;
        const int gi = i0 + row;
        const int giq = gi < 400 ? gi : 399;
        const long rb = hbase + (long)giq * LD + F;
        float v[DT];
        float s = 0.f;
#pragma unroll
        for (int dt = 0; dt < DT; ++dt) {
            v[dt] = acc[dt][reg] + bf2f(hr[rb + dt * 16 + c]);
            s += v[dt];
        }
#pragma unroll
        for (int off = 1; off <= 8; off <<= 1) s += __shfl_xor(s, off, 64);
        const float mean = s * (1.f / F);
        float vs = 0.f;
#pragma unroll
        for (int dt = 0; dt < DT; ++dt) {
            const float d = v[dt] - mean;
            vs += d * d;
        }
#pragma unroll
        for (int off = 1; off <= 8; off <<= 1) vs += __shfl_xor(vs, off, 64);
        const float rstd = rsqrtf(vs * (1.f / F) + 1e-5f);
        if (gi < 400) {
#pragma unroll
            for (int dt = 0; dt < DT; ++dt) {
                const int col = dt * 16 + c;
                float y = (v[dt] - mean) * rstd * gam[col] + bet[col];
                if (ELU) y = (y > 0.f) ? y : expm1f(y);
                if (OUTB16)
                    ((unsigned short*)xout)[((long)b * 400 + gi) * F + col] = f2bf(y);
                else
                    ((float*)xout)[((long)b * 400 + gi) * F + col] = y;
            }
        }
    }
}

extern "C" void kernel_launch(void* const* d_in, const int* in_sizes, int n_in,
                              void* d_out, int out_size, void* d_ws, size_t ws_size,
                              hipStream_t stream) {
    const float* x    = (const float*)d_in[0];
    const float* adj  = (const float*)d_in[1];
    const float* Wq   = (const float*)d_in[2];
    const float* bq   = (const float*)d_in[3];
    const float* Wk   = (const float*)d_in[4];
    const float* bk   = (const float*)d_in[5];
    const float* Wv   = (const float*)d_in[6];
    const float* bv   = (const float*)d_in[7];
    const float* Wo   = (const float*)d_in[8];
    const float* bo   = (const float*)d_in[9];
    const float* g1W  = (const float*)d_in[10];
    const float* g1a  = (const float*)d_in[11];
    const float* g2W  = (const float*)d_in[12];
    const float* g2a  = (const float*)d_in[13];
    const float* g3W  = (const float*)d_in[14];
    const float* g3a  = (const float*)d_in[15];
    const float* r1W  = (const float*)d_in[16];
    const float* r1b  = (const float*)d_in[17];
    const float* r2W  = (const float*)d_in[18];
    const float* r2b  = (const float*)d_in[19];
    const float* r3W  = (const float*)d_in[20];
    const float* r3b  = (const float*)d_in[21];
    const float* ln1g = (const float*)d_in[22];
    const float* ln1b = (const float*)d_in[23];
    const float* ln2g = (const float*)d_in[24];
    const float* ln2b = (const float*)d_in[25];
    const float* ln3g = (const float*)d_in[26];
    const float* ln3b = (const float*)d_in[27];

    float* out_x = (float*)d_out;              // [25600,128]
    float* attn1 = out_x + 3276800;            // [64,400,400]
    float* attn2 = attn1 + 10240000;
    float* attn3 = attn2 + 10240000;

    char* wsb = (char*)d_ws;
    // R1 [0, 52.4MB): xH bf16 [25600][400] (pre-qkv) -> ctxH bf16 [25600][256]
    //                 -> hrH bf16 [25600][512]   (lifetimes disjoint, stream-serial)
    unsigned short* xH   = (unsigned short*)wsb;
    unsigned short* ctxH = (unsigned short*)wsb;
    unsigned short* hrH  = (unsigned short*)wsb;
    // R2 [52.4, 91.8MB): qkv bf16 [25600][768]; later x2H bf16 [25600][256]
    unsigned short* qkvH = (unsigned short*)(wsb + 52428800);
    unsigned short* x2H  = qkvH;
    // R3 [91.8, 112.2MB): maskbias bf16 [64][400][400]
    unsigned short* maskH = (unsigned short*)(wsb + 91750400);
    // R4: small
    float* srcb = (float*)(wsb + 112230400);   // [25600]
    float* dstb = (float*)(wsb + 112332800);   // [25600]
    unsigned short* wT = (unsigned short*)(wsb + 112435200);
    unsigned short* wTq  = wT;                 // [256][400]
    unsigned short* wTk  = wT + 102400;
    unsigned short* wTv  = wT + 204800;
    unsigned short* wTo  = wT + 307200;        // [400][256]
    unsigned short* wTg1 = wT + 409600;        // [256][400]
    unsigned short* wTr1 = wT + 512000;
    unsigned short* wTg2 = wT + 614400;        // [256][256]
    unsigned short* wTr2 = wT + 679936;
    unsigned short* wTg3 = wT + 745472;        // [128][256]
    unsigned short* wTr3 = wT + 778240;
    float* bqkv = (float*)(wsb + 114057216);   // [768]
    float* bgr1 = bqkv + 768;                  // [512]
    float* bgr2 = bgr1 + 512;                  // [512]
    float* bgr3 = bgr2 + 512;                  // [256]
    unsigned short* xcH = (unsigned short*)attn1;   // xc bf16 in attn1 region (dead before gat_fused1)

    const dim3 b256(256);

    // ---- Phase 0 ----
    build_biases<<<1, b256, 0, stream>>>(bqkv, bq, bk, bv, bgr1, r1b, bgr2, r2b, bgr3, r3b);
    adj2mask<<<dim3(10000), b256, 0, stream>>>(adj, maskH);
    f32_to_bf16<<<dim3(10000), b256, 0, stream>>>(x, xH);
    transpose_to_bf16<<<dim3(8, 13), b256, 0, stream>>>(Wq,  wTq, 400, 256, 256);
    transpose_to_bf16<<<dim3(8, 13), b256, 0, stream>>>(Wk,  wTk, 400, 256, 256);
    transpose_to_bf16<<<dim3(8, 13), b256, 0, stream>>>(Wv,  wTv, 400, 256, 256);
    transpose_to_bf16<<<dim3(13, 8), b256, 0, stream>>>(Wo,  wTo, 256, 400, 400);
    transpose_to_bf16<<<dim3(8, 13), b256, 0, stream>>>(g1W, wTg1, 400, 256, 256);
    transpose_to_bf16<<<dim3(8, 13), b256, 0, stream>>>(r1W, wTr1, 400, 256, 256);
    transpose_to_bf16<<<dim3(8, 8),  b256, 0, stream>>>(g2W, wTg2, 256, 256, 256);
    transpose_to_bf16<<<dim3(8, 8),  b256, 0, stream>>>(r2W, wTr2, 256, 256, 256);
    transpose_to_bf16<<<dim3(4, 8),  b256, 0, stream>>>(g3W, wTg3, 256, 128, 128);
    transpose_to_bf16<<<dim3(4, 8),  b256, 0, stream>>>(r3W, wTr3, 256, 128, 128);

    // ---- Phase 1: MHA ----
    gemm_mfma<true, false, true><<<dim3(3, 400), b256, 0, stream>>>(
        xH, wTq, bqkv, nullptr, qkvH, 400, 768, 400, 768);
    mha_flash_mfma<<<dim3(7, 4, 64), b256, 0, stream>>>(qkvH, maskH, ctxH, 768);
    gemm_mfma<true, true, true><<<dim3(2, 400), b256, 0, stream>>>(
        ctxH, wTo, bo, x, xcH, 256, 400, 256, 400);

    // ---- Phase 2: GAT1 (400 -> 256) ----
    gemm_mfma<true, false, true><<<dim3(2, 400), b256, 0, stream>>>(
        xcH, wTg1, bgr1, nullptr, hrH, 400, 512, 400, 512);
    gat_srcdst_h<256><<<dim3(6400), b256, 0, stream>>>(hrH, g1a, srcb, dstb);
    gat_fused<256, true, true><<<dim3(7, 64), b256, 0, stream>>>(
        srcb, dstb, maskH, hrH, ln1g, ln1b, attn1, x2H);   // xc dead from here

    // ---- Phase 3: GAT2 (256 -> 256) ----
    gemm_mfma<true, false, true><<<dim3(2, 400), b256, 0, stream>>>(
        x2H, wTg2, bgr2, nullptr, hrH, 256, 512, 256, 512);
    gat_srcdst_h<256><<<dim3(6400), b256, 0, stream>>>(hrH, g2a, srcb, dstb);
    gat_fused<256, true, true><<<dim3(7, 64), b256, 0, stream>>>(
        srcb, dstb, maskH, hrH, ln2g, ln2b, attn2, x2H);

    // ---- Phase 4: GAT3 (256 -> 128) ----
    gemm_mfma<true, false, true><<<dim3(1, 400), b256, 0, stream>>>(
        x2H, wTg3, bgr3, nullptr, hrH, 256, 256, 256, 256);
    gat_srcdst_h<128><<<dim3(6400), b256, 0, stream>>>(hrH, g3a, srcb, dstb);
    gat_fused<128, false, false><<<dim3(7, 64), b256, 0, stream>>>(
        srcb, dstb, maskH, hrH, ln3g, ln3b, attn3, out_x);
}